// Round 4
// baseline (604.718 us; speedup 1.0000x reference)
//
#include <hip/hip_runtime.h>
#include <hip/hip_bf16.h>

#define N    8192
#define INF  256
#define OUTF 128
#define ALPHA 0.2f

typedef __attribute__((ext_vector_type(8))) short bf16x8;
typedef __attribute__((ext_vector_type(4))) float f32x4;

__device__ __forceinline__ unsigned short f2bf(float x) {
    union { float f; unsigned u; } v; v.f = x;
    unsigned r = v.u + 0x7fff + ((v.u >> 16) & 1);   // RNE
    return (unsigned short)(r >> 16);
}
__device__ __forceinline__ float bf2f(unsigned short b) {
    union { unsigned u; float f; } v; v.u = ((unsigned)b) << 16;
    return v.f;
}

// ---------------- Kernel 1: WhT_b = blocked bf16 (h@W)^T ; f1 ; f2 ----------
// 16 rows/block, 256 threads, grid 512. hT transposed in LDS; W staged in
// 64-row LDS chunks. Thread (rg,ct): Wh rows rg*2..+1, cols ct*4..+3.
// WhT_b layout: [jblk = j/32][c][j%32] ushort — 8 KB per (jblk) tile, so k2's
// B-fragment loads are lane-contiguous (coalesced).
__global__ __launch_bounds__(256) void k1_wh(
        const float* __restrict__ h, const float* __restrict__ W,
        const float* __restrict__ a,
        unsigned short* __restrict__ WhTb, float* __restrict__ f1, float* __restrict__ f2) {
    __shared__ float hT[INF * 17];        // [k][r] 17.4 KB
    __shared__ float Ws[64 * OUTF];       // 32 KB chunk
    const int t  = threadIdx.x;
    const int i0 = blockIdx.x * 16;

    #pragma unroll
    for (int u = 0; u < 4; ++u) {
        int idx = u * 256 + t;            // 0..1023
        int r   = idx >> 6;               // 0..15 (wave-uniform)
        int kq  = idx & 63;               // lane-consecutive -> coalesced
        float4 hv = *(const float4*)(h + (size_t)(i0 + r) * INF + kq * 4);
        hT[(kq * 4 + 0) * 17 + r] = hv.x;
        hT[(kq * 4 + 1) * 17 + r] = hv.y;
        hT[(kq * 4 + 2) * 17 + r] = hv.z;
        hT[(kq * 4 + 3) * 17 + r] = hv.w;
    }

    const int rg = t >> 5;                // 0..7
    const int ct = t & 31;                // 0..31
    float acc0[4] = {0.f,0.f,0.f,0.f};
    float acc1[4] = {0.f,0.f,0.f,0.f};

    for (int chunk = 0; chunk < 4; ++chunk) {
        const int k0 = chunk * 64;
        __syncthreads();                  // hT ready / previous Ws reads done
        #pragma unroll
        for (int u = 0; u < 8; ++u) {
            int idx = u * 256 + t;
            int kk  = idx >> 5;
            int c4  = (idx & 31) * 4;
            *(float4*)(Ws + kk * OUTF + c4) =
                *(const float4*)(W + (size_t)(k0 + kk) * OUTF + c4);
        }
        __syncthreads();
        #pragma unroll 8
        for (int kk = 0; kk < 64; ++kk) {
            float4 wv = *(const float4*)(Ws + kk * OUTF + ct * 4);
            float hx = hT[(k0 + kk) * 17 + rg * 2];
            float hy = hT[(k0 + kk) * 17 + rg * 2 + 1];
            acc0[0] += hx * wv.x; acc0[1] += hx * wv.y;
            acc0[2] += hx * wv.z; acc0[3] += hx * wv.w;
            acc1[0] += hy * wv.x; acc1[1] += hy * wv.y;
            acc1[2] += hy * wv.z; acc1[3] += hy * wv.w;
        }
    }

    const int r0 = i0 + rg * 2;           // Wh row (= j index), even
    const int jb = r0 >> 5;
    const int jo = r0 & 31;
    #pragma unroll
    for (int cc = 0; cc < 4; ++cc) {
        int c = ct * 4 + cc;
        ushort2 pk;
        pk.x = f2bf(acc0[cc]);
        pk.y = f2bf(acc1[cc]);
        *(ushort2*)(WhTb + (size_t)jb * 4096 + c * 32 + jo) = pk;
    }

    const float4 a1v = *(const float4*)(a + ct * 4);
    const float4 a2v = *(const float4*)(a + OUTF + ct * 4);
    float p10 = acc0[0]*a1v.x + acc0[1]*a1v.y + acc0[2]*a1v.z + acc0[3]*a1v.w;
    float p11 = acc1[0]*a1v.x + acc1[1]*a1v.y + acc1[2]*a1v.z + acc1[3]*a1v.w;
    float p20 = acc0[0]*a2v.x + acc0[1]*a2v.y + acc0[2]*a2v.z + acc0[3]*a2v.w;
    float p21 = acc1[0]*a2v.x + acc1[1]*a2v.y + acc1[2]*a2v.z + acc1[3]*a2v.w;
    #pragma unroll
    for (int off = 16; off > 0; off >>= 1) {
        p10 += __shfl_down(p10, off, 32);
        p11 += __shfl_down(p11, off, 32);
        p20 += __shfl_down(p20, off, 32);
        p21 += __shfl_down(p21, off, 32);
    }
    if (ct == 0) {
        f1[r0] = p10;  f1[r0 + 1] = p11;
        f2[r0] = p20;  f2[r0 + 1] = p21;
    }
}

// ---------------- Kernel 2: MFMA attention, in-block j-split, final output ----
// One-pass masked softmax (exact vs ref; verified rounds 1-3). 16 rows/block,
// grid 512. Wave w owns j in [w*2048, (w+1)*2048); epilogue combines the 4
// waves' acc + den through LDS and writes normalized out directly.
// A-fragment computed in registers from the adj HBM stream (depth-2 prefetch);
// B-fragment is one coalesced 16B L2-hit load from blocked WhT.
__global__ __launch_bounds__(256, 4) void k2_attn(
        const int* __restrict__ adj, const unsigned short* __restrict__ WhTb,
        const float* __restrict__ f1, const float* __restrict__ f2,
        float* __restrict__ out) {
    __shared__ float red[4][16][132];     // 33 KB (pitch 132: conflict-safe)
    __shared__ float den_s[4][16];

    const int t    = threadIdx.x;
    const int w    = t >> 6;              // 0..3 : wave = j-range
    const int ln   = t & 63;
    const int m16  = ln & 15;             // A row within 16-tile
    const int quad = ln >> 4;             // 0..3
    const int i0   = blockIdx.x * 16;
    const int row  = i0 + m16;

    const float f1r = f1[row];
    const int   j0w = w * (N / 4);        // wave's j base
    const int   NT  = (N / 4) / 32;       // 64 K-tiles

    const int*   adjp = adj + (size_t)row * N + j0w + quad * 8;
    const float* f2p  = f2 + j0w + quad * 8;
    const int    laneb = m16 * 32 + quad * 8;   // ushort offset within 8 KB tile

    f32x4 acc[8];
    #pragma unroll
    for (int ct = 0; ct < 8; ++ct) acc[ct] = (f32x4){0.f,0.f,0.f,0.f};
    float dsum = 0.f;

    int4   pfa[2][2];
    float4 pff[2][2];
    auto pref = [&](int jt) {
        int b = jt & 1;
        pfa[b][0] = *(const int4*)  (adjp + (size_t)jt * 32);
        pfa[b][1] = *(const int4*)  (adjp + (size_t)jt * 32 + 4);
        pff[b][0] = *(const float4*)(f2p  + (size_t)jt * 32);
        pff[b][1] = *(const float4*)(f2p  + (size_t)jt * 32 + 4);
    };

    pref(0);
    for (int jt = 0; jt < NT; ++jt) {
        const int b = jt & 1;

        // B fragments: 8 coalesced b128 loads from the contiguous 8 KB tile
        const unsigned short* wp = WhTb + ((size_t)(w * 64 + jt)) * 4096 + laneb;
        bf16x8 bfr[8];
        #pragma unroll
        for (int ct = 0; ct < 8; ++ct)
            bfr[ct] = *(const bf16x8*)(wp + ct * 512);

        if (jt + 1 < NT) pref(jt + 1);    // adj/f2 HBM stream, depth 2

        const int   av[8] = {pfa[b][0].x, pfa[b][0].y, pfa[b][0].z, pfa[b][0].w,
                             pfa[b][1].x, pfa[b][1].y, pfa[b][1].z, pfa[b][1].w};
        const float fv[8] = {pff[b][0].x, pff[b][0].y, pff[b][0].z, pff[b][0].w,
                             pff[b][1].x, pff[b][1].y, pff[b][1].z, pff[b][1].w};
        bf16x8 afrag;
        #pragma unroll
        for (int u = 0; u < 8; ++u) {
            float sc = f1r + fv[u];
            float e  = sc > 0.f ? sc : ALPHA * sc;
            float p  = (av[u] > 0) ? __expf(e) : 0.f;
            unsigned short pb = f2bf(p);
            afrag[u] = (short)pb;
            dsum += bf2f(pb);             // same rounding as MFMA input
        }

        #pragma unroll
        for (int ct = 0; ct < 8; ++ct)
            acc[ct] = __builtin_amdgcn_mfma_f32_16x16x32_bf16(afrag, bfr[ct], acc[ct], 0, 0, 0);
    }

    // wave-local den: sum over the 4 quads of each row
    dsum += __shfl_xor(dsum, 16);
    dsum += __shfl_xor(dsum, 32);
    if (quad == 0) den_s[w][m16] = dsum;

    // stage acc partials: D layout col=lane&15, row=quad*4+reg
    #pragma unroll
    for (int ct = 0; ct < 8; ++ct)
        #pragma unroll
        for (int r = 0; r < 4; ++r)
            red[w][quad * 4 + r][ct * 16 + m16] = acc[ct][r];
    __syncthreads();

    // combine 4 waves, normalize, write out (2048 floats = 512 float4)
    #pragma unroll
    for (int e = 0; e < 2; ++e) {
        int idx = e * 256 + t;
        int r   = idx >> 5;
        int c4  = (idx & 31) * 4;
        float4 s0 = *(const float4*)&red[0][r][c4];
        float4 s1 = *(const float4*)&red[1][r][c4];
        float4 s2 = *(const float4*)&red[2][r][c4];
        float4 s3 = *(const float4*)&red[3][r][c4];
        float dtot = den_s[0][r] + den_s[1][r] + den_s[2][r] + den_s[3][r];
        float inv  = 1.0f / dtot;
        float4 o;
        o.x = (s0.x + s1.x + s2.x + s3.x) * inv;
        o.y = (s0.y + s1.y + s2.y + s3.y) * inv;
        o.z = (s0.z + s1.z + s2.z + s3.z) * inv;
        o.w = (s0.w + s1.w + s2.w + s3.w) * inv;
        *(float4*)(out + (size_t)(i0 + r) * OUTF + c4) = o;
    }
}

extern "C" void kernel_launch(void* const* d_in, const int* in_sizes, int n_in,
                              void* d_out, int out_size, void* d_ws, size_t ws_size,
                              hipStream_t stream) {
    const float* h   = (const float*)d_in[0];   // (8192, 256)
    const int*   adj = (const int*)  d_in[1];   // (8192, 8192)
    const float* W   = (const float*)d_in[2];   // (256, 128)
    const float* a   = (const float*)d_in[3];   // (256, 1)
    float* out = (float*)d_out;                 // (8192, 128)

    unsigned short* WhTb = (unsigned short*)d_ws;   // 2 MB blocked bf16
    float* f1 = (float*)(WhTb + (size_t)N * OUTF);
    float* f2 = f1 + N;

    k1_wh  <<<N / 16, 256, 0, stream>>>(h, W, a, WhTb, f1, f2);
    k2_attn<<<N / 16, 256, 0, stream>>>(adj, WhTb, f1, f2, out);
}

// Round 5
// 527.930 us; speedup vs baseline: 1.1455x; 1.1455x over previous
//
#include <hip/hip_runtime.h>
#include <hip/hip_bf16.h>

#define N    8192
#define INF  256
#define OUTF 128
#define ALPHA 0.2f

typedef __attribute__((ext_vector_type(8))) short bf16x8;
typedef __attribute__((ext_vector_type(4))) float f32x4;

__device__ __forceinline__ unsigned short f2bf(float x) {
    union { float f; unsigned u; } v; v.f = x;
    unsigned r = v.u + 0x7fff + ((v.u >> 16) & 1);   // RNE
    return (unsigned short)(r >> 16);
}
__device__ __forceinline__ float bf2f(unsigned short b) {
    union { unsigned u; float f; } v; v.u = ((unsigned)b) << 16;
    return v.f;
}

// ---------------- Kernel 1: WhT_b = blocked bf16 (h@W)^T ; f1 ; f2 ----------
// 8 rows/block, 256 threads, grid 1024 (4 blocks/CU). hs row-major in LDS:
// coalesced float4 stage, broadcast reads (2-addr = free). W read direct from
// L2 (128 KB, hot), unroll-8 keeps 8 float4 loads in flight. No chunk barriers.
// Thread (rg,ct): row i0+rg, cols ct*4..+3.
__global__ __launch_bounds__(256) void k1_wh(
        const float* __restrict__ h, const float* __restrict__ W,
        const float* __restrict__ a,
        unsigned short* __restrict__ WhTb, float* __restrict__ f1, float* __restrict__ f2) {
    __shared__ float hs[8][INF];          // 8 KB
    const int t  = threadIdx.x;
    const int i0 = blockIdx.x * 8;

    #pragma unroll
    for (int u = 0; u < 2; ++u) {
        int idx = u * 256 + t;            // 0..511
        int r   = idx >> 6;               // 0..7 (wave-uniform)
        int kq  = idx & 63;               // lane-consecutive -> coalesced
        *(float4*)&hs[r][kq * 4] = *(const float4*)(h + (size_t)(i0 + r) * INF + kq * 4);
    }
    __syncthreads();

    const int rg = t >> 5;                // 0..7 : row
    const int ct = t & 31;                // 0..31 : col group
    float acc[4] = {0.f, 0.f, 0.f, 0.f};

    #pragma unroll 8
    for (int k = 0; k < INF; ++k) {
        float4 wv = *(const float4*)(W + (size_t)k * OUTF + ct * 4);
        float  hx = hs[rg][k];
        acc[0] += hx * wv.x; acc[1] += hx * wv.y;
        acc[2] += hx * wv.z; acc[3] += hx * wv.w;
    }

    // blocked WhT write: [jblk=j/32][c][j%32] ushort
    const int r0 = i0 + rg;               // j index
    const int jb = r0 >> 5;
    const int jo = r0 & 31;
    #pragma unroll
    for (int cc = 0; cc < 4; ++cc)
        WhTb[(size_t)jb * 4096 + (ct * 4 + cc) * 32 + jo] = f2bf(acc[cc]);

    const float4 a1v = *(const float4*)(a + ct * 4);
    const float4 a2v = *(const float4*)(a + OUTF + ct * 4);
    float p1 = acc[0]*a1v.x + acc[1]*a1v.y + acc[2]*a1v.z + acc[3]*a1v.w;
    float p2 = acc[0]*a2v.x + acc[1]*a2v.y + acc[2]*a2v.z + acc[3]*a2v.w;
    #pragma unroll
    for (int off = 16; off > 0; off >>= 1) {
        p1 += __shfl_down(p1, off, 32);
        p2 += __shfl_down(p2, off, 32);
    }
    if (ct == 0) { f1[r0] = p1; f2[r0] = p2; }
}

// ---------------- Kernel 2: MFMA attention, 8-wave in-block j-split ----------
// One-pass masked softmax (exact vs ref; verified rounds 1-4). 16 rows/block,
// 512 threads, grid 512 (2 blocks/CU = 16 waves/CU). Wave w owns j in
// [w*1024,(w+1)*1024), NT=32 K-steps. A-fragment built in registers from the
// adj HBM stream; NAMED double-buffer prefetch (no runtime-indexed locals ->
// no scratch spill). B-fragment: coalesced 16B L2 loads from blocked WhT.
// Epilogue combines 8 waves' acc+den via LDS, writes normalized out.
struct PF { int4 a0, a1; float4 g0, g1; };

__device__ __forceinline__ PF ldpf(const int* __restrict__ ap,
                                   const float* __restrict__ gp, int jt) {
    PF p;
    p.a0 = *(const int4*)  (ap + (size_t)jt * 32);
    p.a1 = *(const int4*)  (ap + (size_t)jt * 32 + 4);
    p.g0 = *(const float4*)(gp + (size_t)jt * 32);
    p.g1 = *(const float4*)(gp + (size_t)jt * 32 + 4);
    return p;
}

#define EXP1(AV, FV, IDX)                                                   \
    {                                                                       \
        float s_ = f1r + (FV);                                              \
        float e_ = s_ > 0.f ? s_ : ALPHA * s_;                              \
        float p_ = ((AV) > 0) ? __expf(e_) : 0.f;                           \
        unsigned short pb_ = f2bf(p_);                                      \
        afrag[IDX] = (short)pb_;                                            \
        dsum += bf2f(pb_);                                                  \
    }

#define K2ITER(PFV, JT)                                                     \
    {                                                                       \
        const unsigned short* wp_ = WhTb + ((size_t)(w * 32 + (JT))) * 4096 + laneb; \
        bf16x8 b0_ = *(const bf16x8*)(wp_);                                 \
        bf16x8 b1_ = *(const bf16x8*)(wp_ + 512);                           \
        bf16x8 b2_ = *(const bf16x8*)(wp_ + 1024);                          \
        bf16x8 b3_ = *(const bf16x8*)(wp_ + 1536);                          \
        bf16x8 b4_ = *(const bf16x8*)(wp_ + 2048);                          \
        bf16x8 b5_ = *(const bf16x8*)(wp_ + 2560);                          \
        bf16x8 b6_ = *(const bf16x8*)(wp_ + 3072);                          \
        bf16x8 b7_ = *(const bf16x8*)(wp_ + 3584);                          \
        int4 A0_ = PFV.a0, A1_ = PFV.a1;                                    \
        float4 F0_ = PFV.g0, F1_ = PFV.g1;                                  \
        if ((JT) + 2 < NT) PFV = ldpf(adjp, f2p, (JT) + 2);                 \
        bf16x8 afrag;                                                       \
        EXP1(A0_.x, F0_.x, 0) EXP1(A0_.y, F0_.y, 1)                         \
        EXP1(A0_.z, F0_.z, 2) EXP1(A0_.w, F0_.w, 3)                         \
        EXP1(A1_.x, F1_.x, 4) EXP1(A1_.y, F1_.y, 5)                         \
        EXP1(A1_.z, F1_.z, 6) EXP1(A1_.w, F1_.w, 7)                         \
        acc0 = __builtin_amdgcn_mfma_f32_16x16x32_bf16(afrag, b0_, acc0, 0, 0, 0); \
        acc1 = __builtin_amdgcn_mfma_f32_16x16x32_bf16(afrag, b1_, acc1, 0, 0, 0); \
        acc2 = __builtin_amdgcn_mfma_f32_16x16x32_bf16(afrag, b2_, acc2, 0, 0, 0); \
        acc3 = __builtin_amdgcn_mfma_f32_16x16x32_bf16(afrag, b3_, acc3, 0, 0, 0); \
        acc4 = __builtin_amdgcn_mfma_f32_16x16x32_bf16(afrag, b4_, acc4, 0, 0, 0); \
        acc5 = __builtin_amdgcn_mfma_f32_16x16x32_bf16(afrag, b5_, acc5, 0, 0, 0); \
        acc6 = __builtin_amdgcn_mfma_f32_16x16x32_bf16(afrag, b6_, acc6, 0, 0, 0); \
        acc7 = __builtin_amdgcn_mfma_f32_16x16x32_bf16(afrag, b7_, acc7, 0, 0, 0); \
    }

__global__ __launch_bounds__(512, 4) void k2_attn(
        const int* __restrict__ adj, const unsigned short* __restrict__ WhTb,
        const float* __restrict__ f1, const float* __restrict__ f2,
        float* __restrict__ out) {
    __shared__ float red[8][16][132];     // 67.6 KB (pitch 132: 2-way max = free)
    __shared__ float den_s[8][16];

    const int t    = threadIdx.x;
    const int w    = t >> 6;              // 0..7 : wave = j-range
    const int ln   = t & 63;
    const int m16  = ln & 15;             // A row within 16-tile
    const int quad = ln >> 4;             // 0..3
    const int i0   = blockIdx.x * 16;
    const int row  = i0 + m16;

    const float f1r = f1[row];
    const int   j0w = w * (N / 8);        // wave's j base
    const int   NT  = (N / 8) / 32;       // 32 K-steps

    const int*   adjp  = adj + (size_t)row * N + j0w + quad * 8;
    const float* f2p   = f2 + j0w + quad * 8;
    const int    laneb = m16 * 32 + quad * 8;   // ushort offset in 8 KB j-tile

    f32x4 acc0 = {0.f,0.f,0.f,0.f}, acc1 = {0.f,0.f,0.f,0.f};
    f32x4 acc2 = {0.f,0.f,0.f,0.f}, acc3 = {0.f,0.f,0.f,0.f};
    f32x4 acc4 = {0.f,0.f,0.f,0.f}, acc5 = {0.f,0.f,0.f,0.f};
    f32x4 acc6 = {0.f,0.f,0.f,0.f}, acc7 = {0.f,0.f,0.f,0.f};
    float dsum = 0.f;

    PF pf0 = ldpf(adjp, f2p, 0);          // named buffers: depth-2, no arrays
    PF pf1 = ldpf(adjp, f2p, 1);

    for (int jt = 0; jt < NT; jt += 2) {
        K2ITER(pf0, jt)
        K2ITER(pf1, jt + 1)
    }

    // den: sum the 4 quads of each row within the wave
    dsum += __shfl_xor(dsum, 16);
    dsum += __shfl_xor(dsum, 32);
    if (quad == 0) den_s[w][m16] = dsum;

    // stage acc partials: D layout col=lane&15, row=quad*4+reg
    #pragma unroll
    for (int r = 0; r < 4; ++r) {
        red[w][quad * 4 + r][0 * 16 + m16] = acc0[r];
        red[w][quad * 4 + r][1 * 16 + m16] = acc1[r];
        red[w][quad * 4 + r][2 * 16 + m16] = acc2[r];
        red[w][quad * 4 + r][3 * 16 + m16] = acc3[r];
        red[w][quad * 4 + r][4 * 16 + m16] = acc4[r];
        red[w][quad * 4 + r][5 * 16 + m16] = acc5[r];
        red[w][quad * 4 + r][6 * 16 + m16] = acc6[r];
        red[w][quad * 4 + r][7 * 16 + m16] = acc7[r];
    }
    __syncthreads();

    // combine 8 waves, normalize, write out (512 threads x 1 float4 = 16x128)
    {
        int r  = t >> 5;                  // 0..15
        int c4 = (t & 31) * 4;
        float4 sv = {0.f,0.f,0.f,0.f};
        float dtot = 0.f;
        #pragma unroll
        for (int ww = 0; ww < 8; ++ww) {
            float4 v = *(const float4*)&red[ww][r][c4];
            sv.x += v.x; sv.y += v.y; sv.z += v.z; sv.w += v.w;
            dtot += den_s[ww][r];
        }
        const float inv = 1.0f / dtot;
        float4 o = {sv.x * inv, sv.y * inv, sv.z * inv, sv.w * inv};
        *(float4*)(out + (size_t)(i0 + r) * OUTF + c4) = o;
    }
}

extern "C" void kernel_launch(void* const* d_in, const int* in_sizes, int n_in,
                              void* d_out, int out_size, void* d_ws, size_t ws_size,
                              hipStream_t stream) {
    const float* h   = (const float*)d_in[0];   // (8192, 256)
    const int*   adj = (const int*)  d_in[1];   // (8192, 8192)
    const float* W   = (const float*)d_in[2];   // (256, 128)
    const float* a   = (const float*)d_in[3];   // (256, 1)
    float* out = (float*)d_out;                 // (8192, 128)

    unsigned short* WhTb = (unsigned short*)d_ws;   // 2 MB blocked bf16
    float* f1 = (float*)(WhTb + (size_t)N * OUTF);
    float* f2 = f1 + N;

    k1_wh  <<<N / 8, 256, 0, stream>>>(h, W, a, WhTb, f1, f2);
    k2_attn<<<N / 16, 512, 0, stream>>>(adj, WhTb, f1, f2, out);
}

// Round 6
// 452.263 us; speedup vs baseline: 1.3371x; 1.1673x over previous
//
#include <hip/hip_runtime.h>
#include <hip/hip_bf16.h>

#define N    8192
#define INF  256
#define OUTF 128
#define ALPHA 0.2f

typedef __attribute__((ext_vector_type(8))) short bf16x8;
typedef __attribute__((ext_vector_type(4))) float f32x4;

__device__ __forceinline__ unsigned short f2bf(float x) {
    union { float f; unsigned u; } v; v.f = x;
    unsigned r = v.u + 0x7fff + ((v.u >> 16) & 1);   // RNE
    return (unsigned short)(r >> 16);
}
__device__ __forceinline__ float bf2f(unsigned short b) {
    union { unsigned u; float f; } v; v.u = ((unsigned)b) << 16;
    return v.f;
}

// ---------------- Kernel 1: WhT_b = blocked bf16 (h@W)^T ; f1 ; f2 ----------
// 8 rows/block, 256 threads, grid 1024. hs row-major in LDS: coalesced float4
// stage, broadcast reads. W direct from L2, unroll-8. Thread (rg,ct): row
// i0+rg, cols ct*4..+3. WhT_b layout: [jblk=j/32][c][j%32] ushort (8 KB/tile)
// so k2's B-fragment loads are lane-contiguous.
__global__ __launch_bounds__(256) void k1_wh(
        const float* __restrict__ h, const float* __restrict__ W,
        const float* __restrict__ a,
        unsigned short* __restrict__ WhTb, float* __restrict__ f1, float* __restrict__ f2) {
    __shared__ float hs[8][INF];          // 8 KB
    const int t  = threadIdx.x;
    const int i0 = blockIdx.x * 8;

    #pragma unroll
    for (int u = 0; u < 2; ++u) {
        int idx = u * 256 + t;            // 0..511
        int r   = idx >> 6;               // 0..7 (wave-uniform)
        int kq  = idx & 63;               // lane-consecutive -> coalesced
        *(float4*)&hs[r][kq * 4] = *(const float4*)(h + (size_t)(i0 + r) * INF + kq * 4);
    }
    __syncthreads();

    const int rg = t >> 5;                // 0..7 : row
    const int ct = t & 31;                // 0..31 : col group
    float acc[4] = {0.f, 0.f, 0.f, 0.f};

    #pragma unroll 8
    for (int k = 0; k < INF; ++k) {
        float4 wv = *(const float4*)(W + (size_t)k * OUTF + ct * 4);
        float  hx = hs[rg][k];
        acc[0] += hx * wv.x; acc[1] += hx * wv.y;
        acc[2] += hx * wv.z; acc[3] += hx * wv.w;
    }

    const int r0 = i0 + rg;               // j index
    const int jb = r0 >> 5;
    const int jo = r0 & 31;
    #pragma unroll
    for (int cc = 0; cc < 4; ++cc)
        WhTb[(size_t)jb * 4096 + (ct * 4 + cc) * 32 + jo] = f2bf(acc[cc]);

    const float4 a1v = *(const float4*)(a + ct * 4);
    const float4 a2v = *(const float4*)(a + OUTF + ct * 4);
    float p1 = acc[0]*a1v.x + acc[1]*a1v.y + acc[2]*a1v.z + acc[3]*a1v.w;
    float p2 = acc[0]*a2v.x + acc[1]*a2v.y + acc[2]*a2v.z + acc[3]*a2v.w;
    #pragma unroll
    for (int off = 16; off > 0; off >>= 1) {
        p1 += __shfl_down(p1, off, 32);
        p2 += __shfl_down(p2, off, 32);
    }
    if (ct == 0) { f1[r0] = p1; f2[r0] = p2; }
}

// ---------------- Kernel 2: MFMA attention, 4-wave in-block j-split ----------
// One-pass masked softmax (exact vs ref; verified rounds 1-5). 16 rows/block,
// 256 threads, grid 512. Wave w owns j in [w*2048,(w+1)*2048), NT=64 K-steps.
// Prefetch is adj-ONLY (named double buffer, 8 regs each): f2 (8 KB) and WhTb
// (2 MB) are L2-hot and loaded in-iteration. __launch_bounds__(256,3) gives a
// 170-reg budget (~40 regs headroom) so nothing can spill to scratch.
struct PFA { int4 a0, a1; };

__device__ __forceinline__ PFA ldadj(const int* __restrict__ ap, int jt) {
    PFA p;
    p.a0 = *(const int4*)(ap + (size_t)jt * 32);
    p.a1 = *(const int4*)(ap + (size_t)jt * 32 + 4);
    return p;
}

#define EXP1(AV, FV, IDX)                                                   \
    {                                                                       \
        float s_ = f1r + (FV);                                              \
        float e_ = s_ > 0.f ? s_ : ALPHA * s_;                              \
        float p_ = ((AV) > 0) ? __expf(e_) : 0.f;                           \
        unsigned short pb_ = f2bf(p_);                                      \
        afrag[IDX] = (short)pb_;                                            \
        dsum += bf2f(pb_);                                                  \
    }

#define K2STEP(PFV, JT)                                                     \
    {                                                                       \
        const unsigned short* wp_ = WhTb + ((size_t)(w * 64 + (JT))) * 4096 + laneb; \
        bf16x8 b0_ = *(const bf16x8*)(wp_);                                 \
        bf16x8 b1_ = *(const bf16x8*)(wp_ + 512);                           \
        bf16x8 b2_ = *(const bf16x8*)(wp_ + 1024);                          \
        bf16x8 b3_ = *(const bf16x8*)(wp_ + 1536);                          \
        bf16x8 b4_ = *(const bf16x8*)(wp_ + 2048);                          \
        bf16x8 b5_ = *(const bf16x8*)(wp_ + 2560);                          \
        bf16x8 b6_ = *(const bf16x8*)(wp_ + 3072);                          \
        bf16x8 b7_ = *(const bf16x8*)(wp_ + 3584);                          \
        float4 F0_ = *(const float4*)(f2p + (size_t)(JT) * 32);             \
        float4 F1_ = *(const float4*)(f2p + (size_t)(JT) * 32 + 4);         \
        int4 A0_ = PFV.a0, A1_ = PFV.a1;                                    \
        if ((JT) + 2 < NT) PFV = ldadj(adjp, (JT) + 2);                     \
        bf16x8 afrag;                                                       \
        EXP1(A0_.x, F0_.x, 0) EXP1(A0_.y, F0_.y, 1)                         \
        EXP1(A0_.z, F0_.z, 2) EXP1(A0_.w, F0_.w, 3)                         \
        EXP1(A1_.x, F1_.x, 4) EXP1(A1_.y, F1_.y, 5)                         \
        EXP1(A1_.z, F1_.z, 6) EXP1(A1_.w, F1_.w, 7)                         \
        acc0 = __builtin_amdgcn_mfma_f32_16x16x32_bf16(afrag, b0_, acc0, 0, 0, 0); \
        acc1 = __builtin_amdgcn_mfma_f32_16x16x32_bf16(afrag, b1_, acc1, 0, 0, 0); \
        acc2 = __builtin_amdgcn_mfma_f32_16x16x32_bf16(afrag, b2_, acc2, 0, 0, 0); \
        acc3 = __builtin_amdgcn_mfma_f32_16x16x32_bf16(afrag, b3_, acc3, 0, 0, 0); \
        acc4 = __builtin_amdgcn_mfma_f32_16x16x32_bf16(afrag, b4_, acc4, 0, 0, 0); \
        acc5 = __builtin_amdgcn_mfma_f32_16x16x32_bf16(afrag, b5_, acc5, 0, 0, 0); \
        acc6 = __builtin_amdgcn_mfma_f32_16x16x32_bf16(afrag, b6_, acc6, 0, 0, 0); \
        acc7 = __builtin_amdgcn_mfma_f32_16x16x32_bf16(afrag, b7_, acc7, 0, 0, 0); \
    }

__global__ __launch_bounds__(256, 3) void k2_attn(
        const int* __restrict__ adj, const unsigned short* __restrict__ WhTb,
        const float* __restrict__ f1, const float* __restrict__ f2,
        float* __restrict__ out) {
    __shared__ float red[4][16][132];     // 33.8 KB (pitch 132: 2-way max = free)
    __shared__ float den_s[4][16];

    const int t    = threadIdx.x;
    const int w    = t >> 6;              // 0..3 : wave = j-range
    const int ln   = t & 63;
    const int m16  = ln & 15;             // A row within 16-tile
    const int quad = ln >> 4;             // 0..3
    const int i0   = blockIdx.x * 16;
    const int row  = i0 + m16;

    const float f1r = f1[row];
    const int   j0w = w * (N / 4);        // wave's j base
    const int   NT  = (N / 4) / 32;       // 64 K-steps

    const int*   adjp  = adj + (size_t)row * N + j0w + quad * 8;
    const float* f2p   = f2 + j0w + quad * 8;
    const int    laneb = m16 * 32 + quad * 8;   // ushort offset in 8 KB j-tile

    f32x4 acc0 = {0.f,0.f,0.f,0.f}, acc1 = {0.f,0.f,0.f,0.f};
    f32x4 acc2 = {0.f,0.f,0.f,0.f}, acc3 = {0.f,0.f,0.f,0.f};
    f32x4 acc4 = {0.f,0.f,0.f,0.f}, acc5 = {0.f,0.f,0.f,0.f};
    f32x4 acc6 = {0.f,0.f,0.f,0.f}, acc7 = {0.f,0.f,0.f,0.f};
    float dsum = 0.f;

    PFA pf0 = ldadj(adjp, 0);             // adj-only depth-2, named buffers
    PFA pf1 = ldadj(adjp, 1);

    for (int jt = 0; jt < NT; jt += 2) {
        K2STEP(pf0, jt)
        K2STEP(pf1, jt + 1)
    }

    // den: sum the 4 quads of each row within the wave
    dsum += __shfl_xor(dsum, 16);
    dsum += __shfl_xor(dsum, 32);
    if (quad == 0) den_s[w][m16] = dsum;

    // stage acc partials: D layout col=lane&15, row=quad*4+reg
    #pragma unroll
    for (int r = 0; r < 4; ++r) {
        red[w][quad * 4 + r][0 * 16 + m16] = acc0[r];
        red[w][quad * 4 + r][1 * 16 + m16] = acc1[r];
        red[w][quad * 4 + r][2 * 16 + m16] = acc2[r];
        red[w][quad * 4 + r][3 * 16 + m16] = acc3[r];
        red[w][quad * 4 + r][4 * 16 + m16] = acc4[r];
        red[w][quad * 4 + r][5 * 16 + m16] = acc5[r];
        red[w][quad * 4 + r][6 * 16 + m16] = acc6[r];
        red[w][quad * 4 + r][7 * 16 + m16] = acc7[r];
    }
    __syncthreads();

    // combine 4 waves, normalize, write out (256 threads x 2 float4 = 16x128)
    #pragma unroll
    for (int e = 0; e < 2; ++e) {
        int idx = e * 256 + t;
        int r   = idx >> 5;               // 0..15
        int c4  = (idx & 31) * 4;
        float4 s0 = *(const float4*)&red[0][r][c4];
        float4 s1 = *(const float4*)&red[1][r][c4];
        float4 s2 = *(const float4*)&red[2][r][c4];
        float4 s3 = *(const float4*)&red[3][r][c4];
        float dtot = den_s[0][r] + den_s[1][r] + den_s[2][r] + den_s[3][r];
        float inv  = 1.0f / dtot;
        float4 o;
        o.x = (s0.x + s1.x + s2.x + s3.x) * inv;
        o.y = (s0.y + s1.y + s2.y + s3.y) * inv;
        o.z = (s0.z + s1.z + s2.z + s3.z) * inv;
        o.w = (s0.w + s1.w + s2.w + s3.w) * inv;
        *(float4*)(out + (size_t)(i0 + r) * OUTF + c4) = o;
    }
}

extern "C" void kernel_launch(void* const* d_in, const int* in_sizes, int n_in,
                              void* d_out, int out_size, void* d_ws, size_t ws_size,
                              hipStream_t stream) {
    const float* h   = (const float*)d_in[0];   // (8192, 256)
    const int*   adj = (const int*)  d_in[1];   // (8192, 8192)
    const float* W   = (const float*)d_in[2];   // (256, 128)
    const float* a   = (const float*)d_in[3];   // (256, 1)
    float* out = (float*)d_out;                 // (8192, 128)

    unsigned short* WhTb = (unsigned short*)d_ws;   // 2 MB blocked bf16
    float* f1 = (float*)(WhTb + (size_t)N * OUTF);
    float* f2 = f1 + N;

    k1_wh  <<<N / 8, 256, 0, stream>>>(h, W, a, WhTb, f1, f2);
    k2_attn<<<N / 16, 256, 0, stream>>>(adj, WhTb, f1, f2, out);
}